// Round 1
// baseline (490.886 us; speedup 1.0000x reference)
//
#include <hip/hip_runtime.h>
#include <math.h>

#define BATCH 2
#define TSTEPS 8

typedef __attribute__((ext_vector_type(8))) short s16x8;   // 8 bf16
typedef __attribute__((ext_vector_type(4))) float f32x4;   // MFMA accum

__device__ __forceinline__ float hsig(float v){ return fminf(fmaxf(0.2f*v+0.5f,0.f),1.f); }
__device__ __forceinline__ ushort f2bf(float f){
    uint u = __builtin_bit_cast(uint, f);
    u = (u + 0x7FFFu + ((u >> 16) & 1u)) >> 16;
    return (ushort)u;
}
__device__ __forceinline__ uint pack2bf(float lo, float hi){
    return (uint)f2bf(lo) | ((uint)f2bf(hi) << 16);
}

// pack W[k][g*Co+co] fp32 -> fragment-linear bf16:
// dst[((t_n*KCH + c)*64 + lane)*8 + j] = W[k=c*32+quad*8+j][n'=t_n*16+l16 = co*4+g]
template<int KCH, int Co>
__device__ __forceinline__ void packw(const float* __restrict__ W, ushort* __restrict__ dst, int d){
    int j = d & 7, lane = (d >> 3) & 63;
    int q = lane >> 4, l = lane & 15;
    int rest = d >> 9;
    int c = rest % KCH, t_n = rest / KCH;
    int k = c*32 + q*8 + j;
    int np = t_n*16 + l;
    int g = np & 3, co = np >> 2;
    dst[d] = f2bf(W[(size_t)k*(4*Co) + g*Co + co]);
}

#define SZ_X    786432
#define SZ_WX1  884736
#define SZ_WH1  589824
#define SZ_WX2  294912
#define SZ_WH2  147456
#define SZ_WX3  73728
#define SZ_WH3  36864
#define SZ_PREP (SZ_X+SZ_WX1+SZ_WH1+SZ_WX2+SZ_WH2+SZ_WX3+SZ_WH3)

__global__ void prep_kernel(const float* __restrict__ x,
    const float* __restrict__ Wx1, const float* __restrict__ Wh1,
    const float* __restrict__ Wx2, const float* __restrict__ Wh2,
    const float* __restrict__ Wx3, const float* __restrict__ Wh3,
    ushort* __restrict__ xpad,
    ushort* __restrict__ Wxp1, ushort* __restrict__ Whp1,
    ushort* __restrict__ Wxp2, ushort* __restrict__ Whp2,
    ushort* __restrict__ Wxp3, ushort* __restrict__ Whp3)
{
    int i = blockIdx.x * 256 + threadIdx.x;
    if (i < SZ_X){
        int c = i % 192; int r = i / 192;
        int xx = r % 16; r /= 16; int yy = r % 16; int bt = r / 16;
        xpad[((size_t)bt*18*18 + (yy+1)*18 + (xx+1))*192 + c] = f2bf(x[i]);
        return;
    } i -= SZ_X;
    if (i < SZ_WX1){ packw<54,128>(Wx1, Wxp1, i); return; } i -= SZ_WX1;
    if (i < SZ_WH1){ packw<36,128>(Wh1, Whp1, i); return; } i -= SZ_WH1;
    if (i < SZ_WX2){ packw<36, 64>(Wx2, Wxp2, i); return; } i -= SZ_WX2;
    if (i < SZ_WH2){ packw<18, 64>(Wh2, Whp2, i); return; } i -= SZ_WH2;
    if (i < SZ_WX3){ packw<18, 32>(Wx3, Wxp3, i); return; } i -= SZ_WX3;
    if (i < SZ_WH3){ packw< 9, 32>(Wh3, Whp3, i); }
}

// ---------------------------------------------------------------------------
// Full convx (block1 only): wg 32 px x 128 cols, wave = 32px x 32 cols.
// ---------------------------------------------------------------------------
template<int CI, int CO, int H, int W>
__global__ __launch_bounds__(256) void convx_k(
    const ushort* __restrict__ Apad, const ushort* __restrict__ Wpk,
    const float* __restrict__ bias, float* __restrict__ Zx)
{
    constexpr int W_T = (W < 32) ? W : 32;
    constexpr int ROWS = 32 / W_T;
    constexpr int PR = ROWS + 2, PPX = W_T + 2;
    constexpr int PCI = CI + 8;
    constexpr int KCH = 9*CI/32, CPT = CI/32;
    constexpr int HW = H*W, HP = H+2, WP = W+2;
    constexpr int N4 = 4*CO;
    constexpr int CH8 = CI/8;
    constexpr int TOT = PR*PPX*CH8;

    __shared__ ushort patch[PR*PPX*PCI];
    __shared__ float Zsc[32][132];

    const int tid = threadIdx.x, lane = tid & 63, wave = tid >> 6;
    const int quad = lane >> 4, l16 = lane & 15;
    const int m0 = blockIdx.x * 32;
    const int bt = m0 / HW, rem = m0 - bt*HW;
    const int y0 = rem / W, x0 = rem - (rem/W)*W;

    const ushort* gsrc = Apad + (size_t)bt*HP*WP*CI;
    for (int c = tid; c < TOT; c += 256){
        int pix = c / CH8, ch = c - pix*CH8;
        int prow = pix / PPX, ppx = pix - prow*PPX;
        *(uint4*)&patch[pix*PCI + ch*8] =
            *(const uint4*)(gsrc + ((size_t)(y0+prow)*WP + (x0+ppx))*CI + ch*8);
    }
    __syncthreads();

    const int tn0 = blockIdx.y*8 + wave*2;
    const ushort* bptr0 = Wpk + ((size_t)tn0*KCH*64 + lane)*8;
    const ushort* bptr1 = Wpk + ((size_t)(tn0+1)*KCH*64 + lane)*8;

    int labase[2];
    #pragma unroll
    for (int s = 0; s < 2; ++s){
        int p = s*16 + l16;
        int rp = p / W_T, xp = p - rp*W_T;
        labase[s] = (rp*PPX + xp)*PCI + quad*8;
    }

    f32x4 acc[2][2] = {};
    #pragma unroll
    for (int it = 0; it < KCH; ++it){
        const int tap = it / CPT, ci0 = (it - tap*CPT)*32;
        const int kh = tap/3, kw = tap - (tap/3)*3;
        const int off = (kh*PPX + kw)*PCI + ci0;
        s16x8 b0 = *(const s16x8*)(bptr0 + (size_t)it*512);
        s16x8 b1 = *(const s16x8*)(bptr1 + (size_t)it*512);
        s16x8 a0 = *(const s16x8*)&patch[labase[0] + off];
        s16x8 a1 = *(const s16x8*)&patch[labase[1] + off];
        acc[0][0] = __builtin_amdgcn_mfma_f32_16x16x32_bf16(a0, b0, acc[0][0], 0,0,0);
        acc[0][1] = __builtin_amdgcn_mfma_f32_16x16x32_bf16(a0, b1, acc[0][1], 0,0,0);
        acc[1][0] = __builtin_amdgcn_mfma_f32_16x16x32_bf16(a1, b0, acc[1][0], 0,0,0);
        acc[1][1] = __builtin_amdgcn_mfma_f32_16x16x32_bf16(a1, b1, acc[1][1], 0,0,0);
    }

    #pragma unroll
    for (int s = 0; s < 2; ++s){
        #pragma unroll
        for (int nt = 0; nt < 2; ++nt){
            const int col = blockIdx.y*128 + wave*32 + nt*16 + l16;
            const float bv = bias[(col & 3)*CO + (col >> 2)];
            #pragma unroll
            for (int r = 0; r < 4; ++r)
                Zsc[s*16 + quad*4 + r][wave*32 + nt*16 + l16] = acc[s][nt][r] + bv;
        }
    }
    __syncthreads();

    #pragma unroll
    for (int i = 0; i < 4; ++i){
        int c = i*256 + tid;
        int row = c >> 5, cc = (c & 31) << 2;
        *(float4*)&Zx[(size_t)(m0+row)*N4 + blockIdx.y*128 + cc] = *(float4*)&Zsc[row][cc];
    }
}

// ---------------------------------------------------------------------------
// Device role: conv-x for ONE time slice t (same body as convx_k, slice-based).
// ---------------------------------------------------------------------------
template<int CI, int CO, int H, int W>
__device__ __forceinline__ void conv_slice_role(char* smem, int lbid, int t,
    const ushort* __restrict__ Apad, const ushort* __restrict__ Wpk,
    const float* __restrict__ bias, float* __restrict__ Zx)
{
    constexpr int W_T = (W < 32) ? W : 32;
    constexpr int PR = (32/W_T) + 2, PPX = W_T + 2;
    constexpr int PCI = CI + 8;
    constexpr int KCH = 9*CI/32, CPT = CI/32;
    constexpr int HW = H*W, HP = H+2, WP = W+2;
    constexpr int N4 = 4*CO;
    constexpr int CH8 = CI/8;
    constexpr int TOT = PR*PPX*CH8;
    constexpr int TPB = HW/32;
    constexpr int PXT = 2*TPB;

    ushort* patch = (ushort*)smem;
    float* Zsc = (float*)(smem + PR*PPX*PCI*2);   // [32][132]

    const int tid = threadIdx.x, lane = tid & 63, wave = tid >> 6;
    const int quad = lane >> 4, l16 = lane & 15;
    const int lx = lbid % PXT, ly = lbid / PXT;
    const int b = lx / TPB;
    const int idx0 = (lx - b*TPB)*32;
    const int bt = b*TSTEPS + t;
    const int m0 = bt*HW + idx0;
    const int y0 = idx0 / W, x0 = idx0 - (idx0/W)*W;

    const ushort* gsrc = Apad + (size_t)bt*HP*WP*CI;
    for (int c = tid; c < TOT; c += 256){
        int pix = c / CH8, ch = c - pix*CH8;
        int prow = pix / PPX, ppx = pix - prow*PPX;
        *(uint4*)&patch[pix*PCI + ch*8] =
            *(const uint4*)(gsrc + ((size_t)(y0+prow)*WP + (x0+ppx))*CI + ch*8);
    }
    __syncthreads();

    const int tn0 = ly*8 + wave*2;
    const ushort* bptr0 = Wpk + ((size_t)tn0*KCH*64 + lane)*8;
    const ushort* bptr1 = Wpk + ((size_t)(tn0+1)*KCH*64 + lane)*8;

    int labase[2];
    #pragma unroll
    for (int s = 0; s < 2; ++s){
        int p = s*16 + l16;
        int rp = p / W_T, xp = p - rp*W_T;
        labase[s] = (rp*PPX + xp)*PCI + quad*8;
    }

    f32x4 acc[2][2] = {};
    #pragma unroll
    for (int it = 0; it < KCH; ++it){
        const int tap = it / CPT, ci0 = (it - tap*CPT)*32;
        const int kh = tap/3, kw = tap - (tap/3)*3;
        const int off = (kh*PPX + kw)*PCI + ci0;
        s16x8 b0 = *(const s16x8*)(bptr0 + (size_t)it*512);
        s16x8 b1 = *(const s16x8*)(bptr1 + (size_t)it*512);
        s16x8 a0 = *(const s16x8*)&patch[labase[0] + off];
        s16x8 a1 = *(const s16x8*)&patch[labase[1] + off];
        acc[0][0] = __builtin_amdgcn_mfma_f32_16x16x32_bf16(a0, b0, acc[0][0], 0,0,0);
        acc[0][1] = __builtin_amdgcn_mfma_f32_16x16x32_bf16(a0, b1, acc[0][1], 0,0,0);
        acc[1][0] = __builtin_amdgcn_mfma_f32_16x16x32_bf16(a1, b0, acc[1][0], 0,0,0);
        acc[1][1] = __builtin_amdgcn_mfma_f32_16x16x32_bf16(a1, b1, acc[1][1], 0,0,0);
    }

    #pragma unroll
    for (int s = 0; s < 2; ++s){
        #pragma unroll
        for (int nt = 0; nt < 2; ++nt){
            const int col = ly*128 + wave*32 + nt*16 + l16;
            const float bv = bias[(col & 3)*CO + (col >> 2)];
            #pragma unroll
            for (int r = 0; r < 4; ++r)
                Zsc[(s*16 + quad*4 + r)*132 + wave*32 + nt*16 + l16] = acc[s][nt][r] + bv;
        }
    }
    __syncthreads();

    #pragma unroll
    for (int i = 0; i < 4; ++i){
        int c = i*256 + tid;
        int row = c >> 5, cc = (c & 31) << 2;
        *(float4*)&Zx[(size_t)(m0+row)*N4 + ly*128 + cc] = *(float4*)&Zsc[row*132 + cc];
    }
}

// ---------------------------------------------------------------------------
// Device role v2: one LSTM step, 32 px x (64*NTW) cols per wg.
// Waves own n-tiles over the FULL K (no split-K, no Zs/Hs LDS round trips).
// Gate mixing fully in-register: col = co*4+g so the 4 gates of one co live
// in 4 adjacent lanes (g = l16&3); gather via 4 __shfl_xor; the 4-way lane
// redundancy of (c,h) is spent on the 4 upsample quadrants (g>>1, g&1).
// ---------------------------------------------------------------------------
template<int CO, int H, int W, int OUT_BF16, int NTW>
__device__ __forceinline__ void step_role2(char* smem, int lbid, int t, int first,
    const float* __restrict__ Zx, const ushort* __restrict__ Whpk,
    const ushort* __restrict__ hprev, ushort* __restrict__ hnew,
    float* __restrict__ cst,
    const float* __restrict__ gamma, const float* __restrict__ beta,
    const float* __restrict__ mmean, const float* __restrict__ mvar,
    void* __restrict__ outp)
{
    constexpr int W_T = (W < 32) ? W : 32;
    constexpr int PR = (32/W_T) + 2, PPX = W_T + 2;
    constexpr int PCO = CO + 8;
    constexpr int KCH = 9*CO/32, CPT = CO/32;
    constexpr int HW = H*W, HP = H+2, WP = W+2;
    constexpr int N4 = 4*CO;
    constexpr int CH8 = CO/8;
    constexpr int TOT = PR*PPX*CH8;
    constexpr int PT = (BATCH*HW)/32;

    ushort* patch = (ushort*)smem;

    const int tid = threadIdx.x, lane = tid & 63, wave = tid >> 6;
    const int quad = lane >> 4, l16 = lane & 15;
    const int pxt = lbid % PT, colIdx = lbid / PT;
    const int m0 = pxt * 32;
    const int b2 = m0 / HW, rem = m0 - b2*HW;
    const int y0 = rem / W, x0 = rem - (rem/W)*W;
    const int tile0 = colIdx*(4*NTW) + wave*NTW;

    f32x4 acc[2][NTW] = {};

    if (!first){
        const ushort* gsrc = hprev + (size_t)b2*HP*WP*CO;
        for (int c = tid; c < TOT; c += 256){
            int pix = c / CH8, ch = c - pix*CH8;
            int prow = pix / PPX, ppx = pix - prow*PPX;
            *(uint4*)&patch[pix*PCO + ch*8] =
                *(const uint4*)(gsrc + ((size_t)(y0+prow)*WP + (x0+ppx))*CO + ch*8);
        }
        __syncthreads();

        const ushort* bptr[NTW];
        #pragma unroll
        for (int nt = 0; nt < NTW; ++nt)
            bptr[nt] = Whpk + ((size_t)(tile0+nt)*KCH*64 + lane)*8;

        int labase[2];
        #pragma unroll
        for (int s = 0; s < 2; ++s){
            int p = s*16 + l16;
            int rp = p / W_T, xp = p - rp*W_T;
            labase[s] = (rp*PPX + xp)*PCO + quad*8;
        }

        #pragma unroll
        for (int it = 0; it < KCH; ++it){
            const int tap = it / CPT, ci0 = (it - tap*CPT)*32;
            const int kh = tap/3, kw = tap - (tap/3)*3;
            const int off = (kh*PPX + kw)*PCO + ci0;
            s16x8 a0 = *(const s16x8*)&patch[labase[0] + off];
            s16x8 a1 = *(const s16x8*)&patch[labase[1] + off];
            #pragma unroll
            for (int nt = 0; nt < NTW; ++nt){
                s16x8 bb = *(const s16x8*)(bptr[nt] + (size_t)it*512);
                acc[0][nt] = __builtin_amdgcn_mfma_f32_16x16x32_bf16(a0, bb, acc[0][nt], 0,0,0);
                acc[1][nt] = __builtin_amdgcn_mfma_f32_16x16x32_bf16(a1, bb, acc[1][nt], 0,0,0);
            }
        }
    }

    // ------ gates + BN + 2x2 upsample, fully in-register ------
    const int g = l16 & 3;
    const size_t zbase = (size_t)(b2*TSTEPS + t)*HW;

    #pragma unroll
    for (int nt = 0; nt < NTW; ++nt){
        const int tile = tile0 + nt;
        const int co = tile*4 + (l16 >> 2);
        const int col4 = tile*16 + (l16 & 12);
        const float sc = gamma[co]*rsqrtf(mvar[co]+1e-3f);
        const float sh = beta[co] - mmean[co]*sc;
        #pragma unroll
        for (int s = 0; s < 2; ++s){
            #pragma unroll
            for (int r = 0; r < 4; ++r){
                const int px = s*16 + quad*4 + r;
                const int m = m0 + px;
                const int rr = m - b2*HW;
                const float4 zx = *(const float4*)&Zx[(zbase + rr)*N4 + col4];
                const float zsel = (g==0) ? zx.x : (g==1) ? zx.y : (g==2) ? zx.z : zx.w;
                const float z = zsel + acc[s][nt][r];
                const float v = (g==2) ? tanhf(z) : hsig(z);
                const float iv = __shfl_xor(v, g);       // from gate-0 lane
                const float fv = __shfl_xor(v, g^1);     // gate-1
                const float gv = __shfl_xor(v, g^2);     // gate-2 (cell, tanh)
                const float ov = __shfl_xor(v, g^3);     // gate-3
                const float cold = first ? 0.f : cst[(size_t)m*CO + co];
                const float cn = fv*cold + iv*gv;
                const float h = ov * tanhf(cn);
                const int y = rr / W, x = rr - (rr/W)*W;
                if (g == 0){
                    cst[(size_t)m*CO + co] = cn;
                    hnew[((size_t)b2*HP*WP + (y+1)*WP + (x+1))*CO + co] = f2bf(h);
                }
                const float hb = h*sc + sh;
                const int ypos = g >> 1, xpos = g & 1;
                if (OUT_BF16){
                    ushort* o = (ushort*)outp;
                    const size_t opix = ((size_t)(b2*TSTEPS + t)*(2*H+2) + 2*y+1+ypos)*(size_t)(2*W+2) + 2*x+1+xpos;
                    o[opix*CO + co] = f2bf(hb);
                } else {
                    float* o = (float*)outp;
                    const size_t opix = ((size_t)(b2*TSTEPS + t)*(2*H) + 2*y+ypos)*(size_t)(2*W) + 2*x+xpos;
                    o[opix*CO + co] = hb;
                }
            }
        }
    }
}

// ---------------------------------------------------------------------------
// Mega pipeline kernel: up to 5 independent roles per launch.
// LDS = max over roles (C2: 27744 patch + 16896 Zsc = 44640 B).
// Role block counts per launch: S1=64, C2=128, S2=64, C3=256, S3=256 -> 768
// (one resident round at 3 blocks/CU).
// ---------------------------------------------------------------------------
__global__ __launch_bounds__(256) void mega(
    int e1, int e2, int e3, int e4,
    int t1, int t2, int t3, int t4, int t5,
    int f1, int f2, int f3,
    const float* Zx1, const ushort* Whp1, const ushort* h1p, ushort* h1n, float* c1,
    const float* g1, const float* be1, const float* mm1, const float* mv1, ushort* x2pad,
    const ushort* Wxp2, const float* b2v, float* Zx2,
    const ushort* Whp2, const ushort* h2p, ushort* h2n, float* c2,
    const float* g2, const float* be2, const float* mm2, const float* mv2, ushort* x3pad,
    const ushort* Wxp3, const float* b3v, float* Zx3,
    const ushort* Whp3, const ushort* h3p, ushort* h3n, float* c3,
    const float* g3, const float* be3, const float* mm3, const float* mv3, float* outp)
{
    __shared__ __align__(16) char smem[44672];
    const int bid = blockIdx.x;
    if (bid < e1){
        step_role2<128,16,16,1,2>(smem, bid, t1, f1, Zx1, Whp1, h1p, h1n, c1, g1, be1, mm1, mv1, x2pad);
        return;
    }
    if (bid < e2){
        conv_slice_role<128,64,32,32>(smem, bid - e1, t2, x2pad, Wxp2, b2v, Zx2);
        return;
    }
    if (bid < e3){
        step_role2<64,32,32,1,4>(smem, bid - e2, t3, f2, Zx2, Whp2, h2p, h2n, c2, g2, be2, mm2, mv2, x3pad);
        return;
    }
    if (bid < e4){
        conv_slice_role<64,32,64,64>(smem, bid - e3, t4, x3pad, Wxp3, b3v, Zx3);
        return;
    }
    step_role2<32,64,64,0,2>(smem, bid - e4, t5, f3, Zx3, Whp3, h3p, h3n, c3, g3, be3, mm3, mv3, outp);
}

extern "C" void kernel_launch(void* const* d_in, const int* in_sizes, int n_in,
                              void* d_out, int out_size, void* d_ws, size_t ws_size,
                              hipStream_t stream) {
    const float* x   = (const float*)d_in[0];
    const float* Wx1 = (const float*)d_in[1];  const float* Wh1 = (const float*)d_in[2];
    const float* b1  = (const float*)d_in[3];  const float* g1  = (const float*)d_in[4];
    const float* be1 = (const float*)d_in[5];  const float* mm1 = (const float*)d_in[6];
    const float* mv1 = (const float*)d_in[7];
    const float* Wx2 = (const float*)d_in[8];  const float* Wh2 = (const float*)d_in[9];
    const float* b2  = (const float*)d_in[10]; const float* g2  = (const float*)d_in[11];
    const float* be2 = (const float*)d_in[12]; const float* mm2 = (const float*)d_in[13];
    const float* mv2 = (const float*)d_in[14];
    const float* Wx3 = (const float*)d_in[15]; const float* Wh3 = (const float*)d_in[16];
    const float* b3  = (const float*)d_in[17]; const float* g3  = (const float*)d_in[18];
    const float* be3 = (const float*)d_in[19]; const float* mm3 = (const float*)d_in[20];
    const float* mv3 = (const float*)d_in[21];

    char* ws = (char*)d_ws;
    size_t off = 0;
    auto alloc = [&](size_t bytes) { char* p = ws + off; off += (bytes + 255) & ~(size_t)255; return p; };

    float*  Zx1 = (float*)alloc(2097152ull * 4);   //  4096 x 512
    float*  Zx2 = (float*)alloc(4194304ull * 4);   // 16384 x 256
    float*  Zx3 = (float*)alloc(8388608ull * 4);   // 65536 x 128
    float*  c1  = (float*)alloc(65536ull * 4);
    float*  c2  = (float*)alloc(131072ull * 4);
    float*  c3  = (float*)alloc(262144ull * 4);

    // contiguous zero region (one memset): pads + h halo buffers
    char* zbase = alloc(17685504ull);
    ushort* xpad  = (ushort*)zbase;                    //  995,328 u (16x18x18x192)
    ushort* x2pad = xpad  + 995328;                    // 2,367,488 u (16x34x34x128)
    ushort* x3pad = x2pad + 2367488;                   // 4,460,544 u (16x66x66x64)
    ushort* h1A   = x3pad + 4460544;                   //    82,944 u (2x18x18x128)
    ushort* h1B   = h1A + 82944;
    ushort* h2A   = h1B + 82944;                       //   147,968 u (2x34x34x64)
    ushort* h2B   = h2A + 147968;
    ushort* h3A   = h2B + 147968;                      //   278,784 u (2x66x66x32)
    ushort* h3B   = h3A + 278784;

    ushort* Wxp1 = (ushort*)alloc(884736ull * 2);
    ushort* Wxp2 = (ushort*)alloc(294912ull * 2);
    ushort* Wxp3 = (ushort*)alloc(73728ull * 2);
    ushort* Whp1 = (ushort*)alloc(589824ull * 2);
    ushort* Whp2 = (ushort*)alloc(147456ull * 2);
    ushort* Whp3 = (ushort*)alloc(36864ull * 2);

    hipMemsetAsync(zbase, 0, 17685504ull, stream);

    prep_kernel<<<(SZ_PREP + 255) / 256, 256, 0, stream>>>(
        x, Wx1, Wh1, Wx2, Wh2, Wx3, Wh3,
        xpad, Wxp1, Whp1, Wxp2, Whp2, Wxp3, Whp3);

    // block1 conv-x over all t (M = 4096)
    convx_k<192, 128, 16, 16><<<dim3(128, 4), 256, 0, stream>>>(xpad, Wxp1, b1, Zx1);

    // temporal pipeline: L(j) = { S1(j), C2(j-1), S2(j-2), C3(j-3), S3(j-4) }
    for (int j = 0; j < 12; ++j){
        const int a1 = (j < 8),            t1 = a1 ? j     : 0;
        const int a2 = (j >= 1 && j <= 8), tc2 = a2 ? j - 1 : 0;
        const int a3 = (j >= 2 && j <= 9), ts2 = a3 ? j - 2 : 0;
        const int a4 = (j >= 3 && j <= 10), tc3 = a4 ? j - 3 : 0;
        const int a5 = (j >= 4),           ts3 = a5 ? j - 4 : 0;

        const int e1 = a1 ? 64 : 0;
        const int e2 = e1 + (a2 ? 128 : 0);
        const int e3 = e2 + (a3 ? 64 : 0);
        const int e4 = e3 + (a4 ? 256 : 0);
        const int e5 = e4 + (a5 ? 256 : 0);
        if (e5 == 0) continue;

        const ushort* h1p = (t1 & 1) ? h1B : h1A;  ushort* h1n = (t1 & 1) ? h1A : h1B;
        const ushort* h2p = (ts2 & 1) ? h2B : h2A; ushort* h2n = (ts2 & 1) ? h2A : h2B;
        const ushort* h3p = (ts3 & 1) ? h3B : h3A; ushort* h3n = (ts3 & 1) ? h3A : h3B;

        mega<<<dim3(e5), 256, 0, stream>>>(
            e1, e2, e3, e4,
            t1, tc2, ts2, tc3, ts3,
            (t1 == 0), (ts2 == 0), (ts3 == 0),
            Zx1, Whp1, h1p, h1n, c1, g1, be1, mm1, mv1, x2pad,
            Wxp2, b2, Zx2,
            Whp2, h2p, h2n, c2, g2, be2, mm2, mv2, x3pad,
            Wxp3, b3, Zx3,
            Whp3, h3p, h3n, c3, g3, be3, mm3, mv3, (float*)d_out);
    }
}

// Round 2
// 269.103 us; speedup vs baseline: 1.8242x; 1.8242x over previous
//
#include <hip/hip_runtime.h>
#include <math.h>

#define BATCH 2
#define TSTEPS 8

typedef __attribute__((ext_vector_type(8))) short s16x8;   // 8 bf16
typedef __attribute__((ext_vector_type(4))) float f32x4;   // MFMA accum

__device__ __forceinline__ float hsig(float v){ return fminf(fmaxf(0.2f*v+0.5f,0.f),1.f); }
__device__ __forceinline__ ushort f2bf(float f){
    uint u = __builtin_bit_cast(uint, f);
    u = (u + 0x7FFFu + ((u >> 16) & 1u)) >> 16;
    return (ushort)u;
}
__device__ __forceinline__ uint pack2bf(float lo, float hi){
    return (uint)f2bf(lo) | ((uint)f2bf(hi) << 16);
}

// pack W[k][g*Co+co] fp32 -> fragment-linear bf16:
// dst[((t_n*KCH + c)*64 + lane)*8 + j] = W[k=c*32+quad*8+j][n'=t_n*16+l16 = co*4+g]
template<int KCH, int Co>
__device__ __forceinline__ void packw(const float* __restrict__ W, ushort* __restrict__ dst, int d){
    int j = d & 7, lane = (d >> 3) & 63;
    int q = lane >> 4, l = lane & 15;
    int rest = d >> 9;
    int c = rest % KCH, t_n = rest / KCH;
    int k = c*32 + q*8 + j;
    int np = t_n*16 + l;
    int g = np & 3, co = np >> 2;
    dst[d] = f2bf(W[(size_t)k*(4*Co) + g*Co + co]);
}

#define SZ_X    786432
#define SZ_WX1  884736
#define SZ_WH1  589824
#define SZ_WX2  294912
#define SZ_WH2  147456
#define SZ_WX3  73728
#define SZ_WH3  36864
#define SZ_PREP (SZ_X+SZ_WX1+SZ_WH1+SZ_WX2+SZ_WH2+SZ_WX3+SZ_WH3)

__global__ void prep_kernel(const float* __restrict__ x,
    const float* __restrict__ Wx1, const float* __restrict__ Wh1,
    const float* __restrict__ Wx2, const float* __restrict__ Wh2,
    const float* __restrict__ Wx3, const float* __restrict__ Wh3,
    ushort* __restrict__ xpad,
    ushort* __restrict__ Wxp1, ushort* __restrict__ Whp1,
    ushort* __restrict__ Wxp2, ushort* __restrict__ Whp2,
    ushort* __restrict__ Wxp3, ushort* __restrict__ Whp3)
{
    int i = blockIdx.x * 256 + threadIdx.x;
    if (i < SZ_X){
        int c = i % 192; int r = i / 192;
        int xx = r % 16; r /= 16; int yy = r % 16; int bt = r / 16;
        xpad[((size_t)bt*18*18 + (yy+1)*18 + (xx+1))*192 + c] = f2bf(x[i]);
        return;
    } i -= SZ_X;
    if (i < SZ_WX1){ packw<54,128>(Wx1, Wxp1, i); return; } i -= SZ_WX1;
    if (i < SZ_WH1){ packw<36,128>(Wh1, Whp1, i); return; } i -= SZ_WH1;
    if (i < SZ_WX2){ packw<36, 64>(Wx2, Wxp2, i); return; } i -= SZ_WX2;
    if (i < SZ_WH2){ packw<18, 64>(Wh2, Whp2, i); return; } i -= SZ_WH2;
    if (i < SZ_WX3){ packw<18, 32>(Wx3, Wxp3, i); return; } i -= SZ_WX3;
    if (i < SZ_WH3){ packw< 9, 32>(Wh3, Whp3, i); }
}

// ---------------------------------------------------------------------------
// Full convx (block1 only): wg 32 px x 128 cols, wave = 32px x 32 cols.
// LDS: Zsc OVERLAYS patch (live ranges disjoint, barrier between).
// ---------------------------------------------------------------------------
template<int CI, int CO, int H, int W>
__global__ __launch_bounds__(256) void convx_k(
    const ushort* __restrict__ Apad, const ushort* __restrict__ Wpk,
    const float* __restrict__ bias, float* __restrict__ Zx)
{
    constexpr int W_T = (W < 32) ? W : 32;
    constexpr int ROWS = 32 / W_T;
    constexpr int PR = ROWS + 2, PPX = W_T + 2;
    constexpr int PCI = CI + 8;
    constexpr int KCH = 9*CI/32, CPT = CI/32;
    constexpr int HW = H*W, HP = H+2, WP = W+2;
    constexpr int N4 = 4*CO;
    constexpr int CH8 = CI/8;
    constexpr int TOT = PR*PPX*CH8;
    constexpr int PATCH_B = PR*PPX*PCI*2;
    constexpr int SMEM_B = (PATCH_B > 16896 ? PATCH_B : 16896);

    __shared__ __align__(16) char smemx[SMEM_B];
    ushort* patch = (ushort*)smemx;
    float*  Zsc   = (float*)smemx;            // overlay, [32][132]

    const int tid = threadIdx.x, lane = tid & 63, wave = tid >> 6;
    const int quad = lane >> 4, l16 = lane & 15;
    const int m0 = blockIdx.x * 32;
    const int bt = m0 / HW, rem = m0 - bt*HW;
    const int y0 = rem / W, x0 = rem - (rem/W)*W;

    const ushort* gsrc = Apad + (size_t)bt*HP*WP*CI;
    for (int c = tid; c < TOT; c += 256){
        int pix = c / CH8, ch = c - pix*CH8;
        int prow = pix / PPX, ppx = pix - prow*PPX;
        *(uint4*)&patch[pix*PCI + ch*8] =
            *(const uint4*)(gsrc + ((size_t)(y0+prow)*WP + (x0+ppx))*CI + ch*8);
    }
    __syncthreads();

    const int tn0 = blockIdx.y*8 + wave*2;
    const ushort* bptr0 = Wpk + ((size_t)tn0*KCH*64 + lane)*8;
    const ushort* bptr1 = Wpk + ((size_t)(tn0+1)*KCH*64 + lane)*8;

    int labase[2];
    #pragma unroll
    for (int s = 0; s < 2; ++s){
        int p = s*16 + l16;
        int rp = p / W_T, xp = p - rp*W_T;
        labase[s] = (rp*PPX + xp)*PCI + quad*8;
    }

    f32x4 acc[2][2] = {};
    #pragma unroll
    for (int it = 0; it < KCH; ++it){
        const int tap = it / CPT, ci0 = (it - tap*CPT)*32;
        const int kh = tap/3, kw = tap - (tap/3)*3;
        const int off = (kh*PPX + kw)*PCI + ci0;
        s16x8 b0 = *(const s16x8*)(bptr0 + (size_t)it*512);
        s16x8 b1 = *(const s16x8*)(bptr1 + (size_t)it*512);
        s16x8 a0 = *(const s16x8*)&patch[labase[0] + off];
        s16x8 a1 = *(const s16x8*)&patch[labase[1] + off];
        acc[0][0] = __builtin_amdgcn_mfma_f32_16x16x32_bf16(a0, b0, acc[0][0], 0,0,0);
        acc[0][1] = __builtin_amdgcn_mfma_f32_16x16x32_bf16(a0, b1, acc[0][1], 0,0,0);
        acc[1][0] = __builtin_amdgcn_mfma_f32_16x16x32_bf16(a1, b0, acc[1][0], 0,0,0);
        acc[1][1] = __builtin_amdgcn_mfma_f32_16x16x32_bf16(a1, b1, acc[1][1], 0,0,0);
    }
    __syncthreads();   // patch dead; Zsc overlays it

    #pragma unroll
    for (int s = 0; s < 2; ++s){
        #pragma unroll
        for (int nt = 0; nt < 2; ++nt){
            const int col = blockIdx.y*128 + wave*32 + nt*16 + l16;
            const float bv = bias[(col & 3)*CO + (col >> 2)];
            #pragma unroll
            for (int r = 0; r < 4; ++r)
                Zsc[(s*16 + quad*4 + r)*132 + wave*32 + nt*16 + l16] = acc[s][nt][r] + bv;
        }
    }
    __syncthreads();

    #pragma unroll
    for (int i = 0; i < 4; ++i){
        int c = i*256 + tid;
        int row = c >> 5, cc = (c & 31) << 2;
        *(float4*)&Zx[(size_t)(m0+row)*N4 + blockIdx.y*128 + cc] = *(float4*)&Zsc[row*132 + cc];
    }
}

// ---------------------------------------------------------------------------
// Device role: conv-x for ONE time slice t. Zsc overlays patch.
// ---------------------------------------------------------------------------
template<int CI, int CO, int H, int W>
__device__ __forceinline__ void conv_slice_role(char* smem, int lbid, int t,
    const ushort* __restrict__ Apad, const ushort* __restrict__ Wpk,
    const float* __restrict__ bias, float* __restrict__ Zx)
{
    constexpr int W_T = (W < 32) ? W : 32;
    constexpr int PR = (32/W_T) + 2, PPX = W_T + 2;
    constexpr int PCI = CI + 8;
    constexpr int KCH = 9*CI/32, CPT = CI/32;
    constexpr int HW = H*W, HP = H+2, WP = W+2;
    constexpr int N4 = 4*CO;
    constexpr int CH8 = CI/8;
    constexpr int TOT = PR*PPX*CH8;
    constexpr int TPB = HW/32;
    constexpr int PXT = 2*TPB;

    ushort* patch = (ushort*)smem;
    float*  Zsc   = (float*)smem;   // overlay, [32][132]

    const int tid = threadIdx.x, lane = tid & 63, wave = tid >> 6;
    const int quad = lane >> 4, l16 = lane & 15;
    const int lx = lbid % PXT, ly = lbid / PXT;
    const int b = lx / TPB;
    const int idx0 = (lx - b*TPB)*32;
    const int bt = b*TSTEPS + t;
    const int m0 = bt*HW + idx0;
    const int y0 = idx0 / W, x0 = idx0 - (idx0/W)*W;

    const ushort* gsrc = Apad + (size_t)bt*HP*WP*CI;
    for (int c = tid; c < TOT; c += 256){
        int pix = c / CH8, ch = c - pix*CH8;
        int prow = pix / PPX, ppx = pix - prow*PPX;
        *(uint4*)&patch[pix*PCI + ch*8] =
            *(const uint4*)(gsrc + ((size_t)(y0+prow)*WP + (x0+ppx))*CI + ch*8);
    }
    __syncthreads();

    const int tn0 = ly*8 + wave*2;
    const ushort* bptr0 = Wpk + ((size_t)tn0*KCH*64 + lane)*8;
    const ushort* bptr1 = Wpk + ((size_t)(tn0+1)*KCH*64 + lane)*8;

    int labase[2];
    #pragma unroll
    for (int s = 0; s < 2; ++s){
        int p = s*16 + l16;
        int rp = p / W_T, xp = p - rp*W_T;
        labase[s] = (rp*PPX + xp)*PCI + quad*8;
    }

    f32x4 acc[2][2] = {};
    #pragma unroll
    for (int it = 0; it < KCH; ++it){
        const int tap = it / CPT, ci0 = (it - tap*CPT)*32;
        const int kh = tap/3, kw = tap - (tap/3)*3;
        const int off = (kh*PPX + kw)*PCI + ci0;
        s16x8 b0 = *(const s16x8*)(bptr0 + (size_t)it*512);
        s16x8 b1 = *(const s16x8*)(bptr1 + (size_t)it*512);
        s16x8 a0 = *(const s16x8*)&patch[labase[0] + off];
        s16x8 a1 = *(const s16x8*)&patch[labase[1] + off];
        acc[0][0] = __builtin_amdgcn_mfma_f32_16x16x32_bf16(a0, b0, acc[0][0], 0,0,0);
        acc[0][1] = __builtin_amdgcn_mfma_f32_16x16x32_bf16(a0, b1, acc[0][1], 0,0,0);
        acc[1][0] = __builtin_amdgcn_mfma_f32_16x16x32_bf16(a1, b0, acc[1][0], 0,0,0);
        acc[1][1] = __builtin_amdgcn_mfma_f32_16x16x32_bf16(a1, b1, acc[1][1], 0,0,0);
    }
    __syncthreads();   // patch dead; Zsc overlays it

    #pragma unroll
    for (int s = 0; s < 2; ++s){
        #pragma unroll
        for (int nt = 0; nt < 2; ++nt){
            const int col = ly*128 + wave*32 + nt*16 + l16;
            const float bv = bias[(col & 3)*CO + (col >> 2)];
            #pragma unroll
            for (int r = 0; r < 4; ++r)
                Zsc[(s*16 + quad*4 + r)*132 + wave*32 + nt*16 + l16] = acc[s][nt][r] + bv;
        }
    }
    __syncthreads();

    #pragma unroll
    for (int i = 0; i < 4; ++i){
        int c = i*256 + tid;
        int row = c >> 5, cc = (c & 31) << 2;
        *(float4*)&Zx[(size_t)(m0+row)*N4 + ly*128 + cc] = *(float4*)&Zsc[row*132 + cc];
    }
}

// ---------------------------------------------------------------------------
// Device role: one LSTM step (32 px x 32 interleaved cols per wg, split-K over
// 4 waves, LDS reduce, fused gates+BN+2x2 upsample). Zs overlays patch.
// ---------------------------------------------------------------------------
template<int CO, int H, int W, int OUT_BF16>
__device__ __forceinline__ void step_role(char* smem, int lbid, int t, int first,
    const float* __restrict__ Zx, const ushort* __restrict__ Whpk,
    const ushort* __restrict__ hprev, ushort* __restrict__ hnew,
    float* __restrict__ cst,
    const float* __restrict__ gamma, const float* __restrict__ beta,
    const float* __restrict__ mmean, const float* __restrict__ mvar,
    void* __restrict__ outp)
{
    constexpr int W_T = (W < 32) ? W : 32;
    constexpr int PR = (32/W_T) + 2, PPX = W_T + 2;
    constexpr int PCO = CO + 8;
    constexpr int KCH = 9*CO/32, CPT = CO/32;
    constexpr int NJ = (KCH + 3)/4;
    constexpr int HW = H*W, HP = H+2, WP = W+2;
    constexpr int N4 = 4*CO;
    constexpr int CH8 = CO/8;
    constexpr int TOT = PR*PPX*CH8;
    constexpr int PT = (BATCH*HW)/32;

    ushort* patch = (ushort*)smem;
    float* Zs = (float*)smem;                   // overlay, [4][32][36]
    float* Hs = (float*)(smem + 18432);         // [32][8], after Zs

    const int tid = threadIdx.x, lane = tid & 63, wave = tid >> 6;
    const int quad = lane >> 4, l16 = lane & 15;
    const int pxt = lbid % PT, colIdx = lbid / PT;
    const int m0 = pxt * 32;
    const int b2 = m0 / HW, rem = m0 - b2*HW;
    const int y0 = rem / W, x0 = rem - (rem/W)*W;
    const int co0 = colIdx * 8;

    if (!first){
        const ushort* gsrc = hprev + (size_t)b2*HP*WP*CO;
        for (int c = tid; c < TOT; c += 256){
            int pix = c / CH8, ch = c - pix*CH8;
            int prow = pix / PPX, ppx = pix - prow*PPX;
            *(uint4*)&patch[pix*PCO + ch*8] =
                *(const uint4*)(gsrc + ((size_t)(y0+prow)*WP + (x0+ppx))*CO + ch*8);
        }
        __syncthreads();

        const int tn0 = colIdx*2;
        const ushort* bptr0 = Whpk + ((size_t)tn0*KCH*64 + lane)*8;
        const ushort* bptr1 = Whpk + ((size_t)(tn0+1)*KCH*64 + lane)*8;

        int labase[2];
        #pragma unroll
        for (int s = 0; s < 2; ++s){
            int p = s*16 + l16;
            int rp = p / W_T, xp = p - rp*W_T;
            labase[s] = (rp*PPX + xp)*PCO + quad*8;
        }

        f32x4 acc[2][2] = {};
        const int nj = (KCH - wave + 3) >> 2;
        #pragma unroll
        for (int j = 0; j < NJ; ++j){
            if (j < nj){
                const int it = wave + 4*j;
                const int tap = it / CPT, ci0 = (it - tap*CPT)*32;
                const int kh = tap/3, kw = tap - (tap/3)*3;
                const int off = (kh*PPX + kw)*PCO + ci0;
                s16x8 b0 = *(const s16x8*)(bptr0 + (size_t)it*512);
                s16x8 b1 = *(const s16x8*)(bptr1 + (size_t)it*512);
                s16x8 a0 = *(const s16x8*)&patch[labase[0] + off];
                s16x8 a1 = *(const s16x8*)&patch[labase[1] + off];
                acc[0][0] = __builtin_amdgcn_mfma_f32_16x16x32_bf16(a0, b0, acc[0][0], 0,0,0);
                acc[0][1] = __builtin_amdgcn_mfma_f32_16x16x32_bf16(a0, b1, acc[0][1], 0,0,0);
                acc[1][0] = __builtin_amdgcn_mfma_f32_16x16x32_bf16(a1, b0, acc[1][0], 0,0,0);
                acc[1][1] = __builtin_amdgcn_mfma_f32_16x16x32_bf16(a1, b1, acc[1][1], 0,0,0);
            }
        }
        __syncthreads();   // patch dead; Zs overlays it
        #pragma unroll
        for (int s = 0; s < 2; ++s)
            #pragma unroll
            for (int nt = 0; nt < 2; ++nt)
                #pragma unroll
                for (int r = 0; r < 4; ++r)
                    Zs[(wave*32 + s*16 + quad*4 + r)*36 + nt*16 + l16] = acc[s][nt][r];
        __syncthreads();
    }

    // gates: 32 px x 8 co
    {
        const int px = tid >> 3, coin = tid & 7;
        const int m = m0 + px;
        const int rr = m - b2*HW;
        const int co = co0 + coin;
        const size_t zrow = (size_t)(b2*TSTEPS + t)*HW + rr;
        const float4 zx = *(const float4*)&Zx[zrow*N4 + colIdx*32 + coin*4];
        float zi = zx.x, zf = zx.y, zg = zx.z, zo = zx.w;
        if (!first){
            #pragma unroll
            for (int w = 0; w < 4; ++w){
                const float4 s = *(const float4*)&Zs[(w*32 + px)*36 + coin*4];
                zi += s.x; zf += s.y; zg += s.z; zo += s.w;
            }
        }
        const float iv = hsig(zi), fv = hsig(zf);
        const float gv = tanhf(zg), ov = hsig(zo);
        const float cold = first ? 0.f : cst[(size_t)m*CO + co];
        const float cn = fv*cold + iv*gv;
        cst[(size_t)m*CO + co] = cn;
        const float h = ov * tanhf(cn);
        const int y = rr / W, x = rr - (rr/W)*W;
        hnew[((size_t)b2*HP*WP + (y+1)*WP + (x+1))*CO + co] = f2bf(h);
        Hs[px*8 + coin] = (h - mmean[co])*rsqrtf(mvar[co]+1e-3f)*gamma[co] + beta[co];
    }
    __syncthreads();

    if (OUT_BF16){
        if (tid < 128){
            const int px = tid >> 2, q = tid & 3;
            const int ypos = q >> 1, xpos = q & 1;
            const int m = m0 + px;
            const int rr = m - b2*HW;
            const int y = rr / W, x = rr - (rr/W)*W;
            const float* hs = &Hs[px*8];
            uint4 v;
            v.x = pack2bf(hs[0], hs[1]); v.y = pack2bf(hs[2], hs[3]);
            v.z = pack2bf(hs[4], hs[5]); v.w = pack2bf(hs[6], hs[7]);
            ushort* o = (ushort*)outp;
            const size_t opix = ((size_t)(b2*TSTEPS + t)*(2*H+2) + 2*y+1+ypos)*(size_t)(2*W+2) + 2*x+1+xpos;
            *(uint4*)&o[opix*CO + co0] = v;
        }
    } else {
        const int px = tid >> 3, q = (tid >> 1) & 3, half = tid & 1;
        const int ypos = q >> 1, xpos = q & 1;
        const int m = m0 + px;
        const int rr = m - b2*HW;
        const int y = rr / W, x = rr - (rr/W)*W;
        float4 v = *(const float4*)&Hs[px*8 + half*4];
        float* o = (float*)outp;
        const size_t opix = ((size_t)(b2*TSTEPS + t)*(2*H) + 2*y+ypos)*(size_t)(2*W) + 2*x+xpos;
        *(float4*)&o[opix*CO + co0 + half*4] = v;
    }
}

// ---------------------------------------------------------------------------
// Mega pipeline kernel: up to 5 independent roles per launch.
// LDS = max over roles with patch/Z overlay: C2 = 27744 B -> 5 blocks/CU.
// ---------------------------------------------------------------------------
__global__ __launch_bounds__(256) void mega(
    int e1, int e2, int e3, int e4,
    int t1, int t2, int t3, int t4, int t5,
    int f1, int f2, int f3,
    const float* Zx1, const ushort* Whp1, const ushort* h1p, ushort* h1n, float* c1,
    const float* g1, const float* be1, const float* mm1, const float* mv1, ushort* x2pad,
    const ushort* Wxp2, const float* b2v, float* Zx2,
    const ushort* Whp2, const ushort* h2p, ushort* h2n, float* c2,
    const float* g2, const float* be2, const float* mm2, const float* mv2, ushort* x3pad,
    const ushort* Wxp3, const float* b3v, float* Zx3,
    const ushort* Whp3, const ushort* h3p, ushort* h3n, float* c3,
    const float* g3, const float* be3, const float* mm3, const float* mv3, float* outp)
{
    __shared__ __align__(16) char smem[27776];
    const int bid = blockIdx.x;
    if (bid < e1){
        step_role<128,16,16,1>(smem, bid, t1, f1, Zx1, Whp1, h1p, h1n, c1, g1, be1, mm1, mv1, x2pad);
        return;
    }
    if (bid < e2){
        conv_slice_role<128,64,32,32>(smem, bid - e1, t2, x2pad, Wxp2, b2v, Zx2);
        return;
    }
    if (bid < e3){
        step_role<64,32,32,1>(smem, bid - e2, t3, f2, Zx2, Whp2, h2p, h2n, c2, g2, be2, mm2, mv2, x3pad);
        return;
    }
    if (bid < e4){
        conv_slice_role<64,32,64,64>(smem, bid - e3, t4, x3pad, Wxp3, b3v, Zx3);
        return;
    }
    step_role<32,64,64,0>(smem, bid - e4, t5, f3, Zx3, Whp3, h3p, h3n, c3, g3, be3, mm3, mv3, outp);
}

extern "C" void kernel_launch(void* const* d_in, const int* in_sizes, int n_in,
                              void* d_out, int out_size, void* d_ws, size_t ws_size,
                              hipStream_t stream) {
    const float* x   = (const float*)d_in[0];
    const float* Wx1 = (const float*)d_in[1];  const float* Wh1 = (const float*)d_in[2];
    const float* b1  = (const float*)d_in[3];  const float* g1  = (const float*)d_in[4];
    const float* be1 = (const float*)d_in[5];  const float* mm1 = (const float*)d_in[6];
    const float* mv1 = (const float*)d_in[7];
    const float* Wx2 = (const float*)d_in[8];  const float* Wh2 = (const float*)d_in[9];
    const float* b2  = (const float*)d_in[10]; const float* g2  = (const float*)d_in[11];
    const float* be2 = (const float*)d_in[12]; const float* mm2 = (const float*)d_in[13];
    const float* mv2 = (const float*)d_in[14];
    const float* Wx3 = (const float*)d_in[15]; const float* Wh3 = (const float*)d_in[16];
    const float* b3  = (const float*)d_in[17]; const float* g3  = (const float*)d_in[18];
    const float* be3 = (const float*)d_in[19]; const float* mm3 = (const float*)d_in[20];
    const float* mv3 = (const float*)d_in[21];

    char* ws = (char*)d_ws;
    size_t off = 0;
    auto alloc = [&](size_t bytes) { char* p = ws + off; off += (bytes + 255) & ~(size_t)255; return p; };

    float*  Zx1 = (float*)alloc(2097152ull * 4);   //  4096 x 512
    float*  Zx2 = (float*)alloc(4194304ull * 4);   // 16384 x 256
    float*  Zx3 = (float*)alloc(8388608ull * 4);   // 65536 x 128
    float*  c1  = (float*)alloc(65536ull * 4);
    float*  c2  = (float*)alloc(131072ull * 4);
    float*  c3  = (float*)alloc(262144ull * 4);

    // contiguous zero region (one memset): pads + h halo buffers
    char* zbase = alloc(17685504ull);
    ushort* xpad  = (ushort*)zbase;                    //  995,328 u (16x18x18x192)
    ushort* x2pad = xpad  + 995328;                    // 2,367,488 u (16x34x34x128)
    ushort* x3pad = x2pad + 2367488;                   // 4,460,544 u (16x66x66x64)
    ushort* h1A   = x3pad + 4460544;                   //    82,944 u (2x18x18x128)
    ushort* h1B   = h1A + 82944;
    ushort* h2A   = h1B + 82944;                       //   147,968 u (2x34x34x64)
    ushort* h2B   = h2A + 147968;
    ushort* h3A   = h2B + 147968;                      //   278,784 u (2x66x66x32)
    ushort* h3B   = h3A + 278784;

    ushort* Wxp1 = (ushort*)alloc(884736ull * 2);
    ushort* Wxp2 = (ushort*)alloc(294912ull * 2);
    ushort* Wxp3 = (ushort*)alloc(73728ull * 2);
    ushort* Whp1 = (ushort*)alloc(589824ull * 2);
    ushort* Whp2 = (ushort*)alloc(147456ull * 2);
    ushort* Whp3 = (ushort*)alloc(36864ull * 2);

    hipMemsetAsync(zbase, 0, 17685504ull, stream);

    prep_kernel<<<(SZ_PREP + 255) / 256, 256, 0, stream>>>(
        x, Wx1, Wh1, Wx2, Wh2, Wx3, Wh3,
        xpad, Wxp1, Whp1, Wxp2, Whp2, Wxp3, Whp3);

    // block1 conv-x over all t (M = 4096)
    convx_k<192, 128, 16, 16><<<dim3(128, 4), 256, 0, stream>>>(xpad, Wxp1, b1, Zx1);

    // temporal pipeline: L(j) = { S1(j), C2(j-1), S2(j-2), C3(j-3), S3(j-4) }
    for (int j = 0; j < 12; ++j){
        const int a1 = (j < 8),            t1 = a1 ? j     : 0;
        const int a2 = (j >= 1 && j <= 8), tc2 = a2 ? j - 1 : 0;
        const int a3 = (j >= 2 && j <= 9), ts2 = a3 ? j - 2 : 0;
        const int a4 = (j >= 3 && j <= 10), tc3 = a4 ? j - 3 : 0;
        const int a5 = (j >= 4),           ts3 = a5 ? j - 4 : 0;

        const int e1 = a1 ? 256 : 0;
        const int e2 = e1 + (a2 ? 128 : 0);
        const int e3 = e2 + (a3 ? 512 : 0);
        const int e4 = e3 + (a4 ? 256 : 0);
        const int e5 = e4 + (a5 ? 1024 : 0);
        if (e5 == 0) continue;

        const ushort* h1p = (t1 & 1) ? h1B : h1A;  ushort* h1n = (t1 & 1) ? h1A : h1B;
        const ushort* h2p = (ts2 & 1) ? h2B : h2A; ushort* h2n = (ts2 & 1) ? h2A : h2B;
        const ushort* h3p = (ts3 & 1) ? h3B : h3A; ushort* h3n = (ts3 & 1) ? h3A : h3B;

        mega<<<dim3(e5), 256, 0, stream>>>(
            e1, e2, e3, e4,
            t1, tc2, ts2, tc3, ts3,
            (t1 == 0), (ts2 == 0), (ts3 == 0),
            Zx1, Whp1, h1p, h1n, c1, g1, be1, mm1, mv1, x2pad,
            Wxp2, b2, Zx2,
            Whp2, h2p, h2n, c2, g2, be2, mm2, mv2, x3pad,
            Wxp3, b3, Zx3,
            Whp3, h3p, h3n, c3, g3, be3, mm3, mv3, (float*)d_out);
    }
}